// Round 1
// baseline (661.577 us; speedup 1.0000x reference)
//
#include <hip/hip_runtime.h>
#include <math.h>

// Workspace layout (uint32 words):
//  [0] maxbits (atomicMax of |x| bit patterns; non-neg floats order as uints)
//  [1] cand_count
//  [2] sel_bin (top-12-bit bin containing rank k)
//  [3] rank_in_bin
//  [4 .. 4+4096) histogram over top 12 bits of |x| bits
//  [4128 .. ) compacted candidate bit patterns (those in sel_bin)
#define WS_MAXBITS 0
#define WS_COUNT   1
#define WS_SELBIN  2
#define WS_RANK    3
#define WS_HIST    4
#define HIST_WORDS 4096
#define WS_CAND    4128   // word offset => byte offset 16512, 128B-aligned

extern "C" __global__ void __launch_bounds__(256)
k_max_hist(const float* __restrict__ x, long n, unsigned int* __restrict__ ws) {
    __shared__ unsigned int lhist[HIST_WORDS];
    __shared__ unsigned int wred[4];
    for (int i = threadIdx.x; i < HIST_WORDS; i += 256) lhist[i] = 0;
    __syncthreads();

    long n4 = n >> 2;
    const float4* x4 = (const float4*)x;
    unsigned int mymax = 0;
    long stride = (long)gridDim.x * 256;
    for (long i = (long)blockIdx.x * 256 + threadIdx.x; i < n4; i += stride) {
        float4 v = x4[i];
        unsigned int a0 = __float_as_uint(fabsf(v.x));
        unsigned int a1 = __float_as_uint(fabsf(v.y));
        unsigned int a2 = __float_as_uint(fabsf(v.z));
        unsigned int a3 = __float_as_uint(fabsf(v.w));
        mymax = max(mymax, max(max(a0, a1), max(a2, a3)));
        atomicAdd(&lhist[a0 >> 20], 1u);
        atomicAdd(&lhist[a1 >> 20], 1u);
        atomicAdd(&lhist[a2 >> 20], 1u);
        atomicAdd(&lhist[a3 >> 20], 1u);
    }
    // scalar tail (n % 4), handled once by block 0 directly against global
    if (blockIdx.x == 0 && threadIdx.x < (int)(n & 3)) {
        unsigned int a = __float_as_uint(fabsf(x[n4 * 4 + threadIdx.x]));
        atomicAdd(&ws[WS_HIST + (a >> 20)], 1u);
        atomicMax(&ws[WS_MAXBITS], a);
    }

    // wave64 max reduce, then block, then one global atomic
    for (int off = 32; off > 0; off >>= 1)
        mymax = max(mymax, __shfl_down(mymax, off, 64));
    int lane = threadIdx.x & 63, wid = threadIdx.x >> 6;
    if (lane == 0) wred[wid] = mymax;
    __syncthreads();   // also orders all lhist atomics before the flush below
    if (threadIdx.x == 0) {
        unsigned int m = max(max(wred[0], wred[1]), max(wred[2], wred[3]));
        atomicMax(&ws[WS_MAXBITS], m);
    }
    // flush LDS histogram (only ~300 non-zero bins for N(0,1) data)
    for (int i = threadIdx.x; i < HIST_WORDS; i += 256) {
        unsigned int c = lhist[i];
        if (c) atomicAdd(&ws[WS_HIST + i], c);
    }
}

extern "C" __global__ void __launch_bounds__(256)
k_scan(unsigned int* __restrict__ ws, long k) {
    // single block: find bin containing rank k (0-indexed) + rank within bin
    __shared__ unsigned long long partial[256];
    const unsigned int* hist = ws + WS_HIST;
    int base = threadIdx.x * (HIST_WORDS / 256);  // 16 bins per thread
    unsigned long long s = 0;
    for (int i = 0; i < 16; i++) s += hist[base + i];
    partial[threadIdx.x] = s;
    __syncthreads();
    if (threadIdx.x == 0) {
        unsigned long long acc = 0;
        long bin = -1;
        unsigned long long before = 0;
        for (int t = 0; t < 256; t++) {
            unsigned long long ps = partial[t];
            if (bin < 0 && acc + ps > (unsigned long long)k) {
                unsigned long long a2 = acc;
                for (int i = 0; i < 16; i++) {
                    unsigned int c = hist[t * 16 + i];
                    if (a2 + c > (unsigned long long)k) { bin = t * 16 + i; before = a2; break; }
                    a2 += c;
                }
            }
            acc += ps;
        }
        ws[WS_SELBIN] = (unsigned int)bin;
        ws[WS_RANK]   = (unsigned int)((unsigned long long)k - before);
    }
}

extern "C" __global__ void __launch_bounds__(256)
k_quant(const float* __restrict__ x, float* __restrict__ out, long n,
        unsigned int* __restrict__ ws, unsigned int cap) {
    float xmax = __uint_as_float(ws[WS_MAXBITS]);
    unsigned int selbin = ws[WS_SELBIN];
    float scale = 127.0f / xmax;
    float inv = 1.0f / scale;
    unsigned int* cand = ws + WS_CAND;

    long n4 = n >> 2;
    const float4* x4 = (const float4*)x;
    float4* out4 = (float4*)out;
    long stride = (long)gridDim.x * 256;
    for (long i = (long)blockIdx.x * 256 + threadIdx.x; i < n4; i += stride) {
        float4 v = x4[i];
        float4 r;
        r.x = fminf(fmaxf(rintf(v.x * scale), -127.0f), 127.0f) * inv;
        r.y = fminf(fmaxf(rintf(v.y * scale), -127.0f), 127.0f) * inv;
        r.z = fminf(fmaxf(rintf(v.z * scale), -127.0f), 127.0f) * inv;
        r.w = fminf(fmaxf(rintf(v.w * scale), -127.0f), 127.0f) * inv;
        out4[i] = r;
        unsigned int a0 = __float_as_uint(fabsf(v.x));
        unsigned int a1 = __float_as_uint(fabsf(v.y));
        unsigned int a2 = __float_as_uint(fabsf(v.z));
        unsigned int a3 = __float_as_uint(fabsf(v.w));
        if ((a0 >> 20) == selbin) { unsigned int p = atomicAdd(&ws[WS_COUNT], 1u); if (p < cap) cand[p] = a0; }
        if ((a1 >> 20) == selbin) { unsigned int p = atomicAdd(&ws[WS_COUNT], 1u); if (p < cap) cand[p] = a1; }
        if ((a2 >> 20) == selbin) { unsigned int p = atomicAdd(&ws[WS_COUNT], 1u); if (p < cap) cand[p] = a2; }
        if ((a3 >> 20) == selbin) { unsigned int p = atomicAdd(&ws[WS_COUNT], 1u); if (p < cap) cand[p] = a3; }
    }
    if (blockIdx.x == 0 && threadIdx.x < (int)(n & 3)) {
        long i = n4 * 4 + threadIdx.x;
        float v = x[i];
        out[i] = fminf(fmaxf(rintf(v * scale), -127.0f), 127.0f) * inv;
        unsigned int a = __float_as_uint(fabsf(v));
        if ((a >> 20) == selbin) { unsigned int p = atomicAdd(&ws[WS_COUNT], 1u); if (p < cap) cand[p] = a; }
    }
}

extern "C" __global__ void __launch_bounds__(256)
k_select(unsigned int* __restrict__ ws, float* __restrict__ out_last, unsigned int cap) {
    // single block: two-level radix select over compacted candidates.
    // All candidates share the same top-12 bits (sel_bin); resolve bits
    // [10,20) then [0,10) exactly.
    __shared__ unsigned int hist[1024];
    __shared__ unsigned int s_b1, s_j2;
    unsigned int c = ws[WS_COUNT]; if (c > cap) c = cap;
    unsigned int j = ws[WS_RANK];
    unsigned int selbin = ws[WS_SELBIN];
    const unsigned int* cand = ws + WS_CAND;

    for (int i = threadIdx.x; i < 1024; i += 256) hist[i] = 0;
    __syncthreads();
    for (unsigned int i = threadIdx.x; i < c; i += 256)
        atomicAdd(&hist[(cand[i] >> 10) & 1023], 1u);
    __syncthreads();
    if (threadIdx.x == 0) {
        unsigned int acc = 0, b1 = 1023;
        for (int b = 0; b < 1024; b++) {
            unsigned int h = hist[b];
            if (acc + h > j) { b1 = (unsigned int)b; break; }
            acc += h;
        }
        s_b1 = b1; s_j2 = j - acc;
    }
    __syncthreads();
    unsigned int pref = (selbin << 10) | s_b1;
    unsigned int j2 = s_j2;
    for (int i = threadIdx.x; i < 1024; i += 256) hist[i] = 0;
    __syncthreads();
    for (unsigned int i = threadIdx.x; i < c; i += 256) {
        unsigned int u = cand[i];
        if ((u >> 10) == pref) atomicAdd(&hist[u & 1023], 1u);
    }
    __syncthreads();
    if (threadIdx.x == 0) {
        unsigned int acc = 0, b2 = 1023;
        for (int b = 0; b < 1024; b++) {
            unsigned int h = hist[b];
            if (acc + h > j2) { b2 = (unsigned int)b; break; }
            acc += h;
        }
        float clampv = __uint_as_float((pref << 10) | b2);
        // new_buffer = CLAMP_INIT*GAMMA + clamp_value*(1-GAMMA)
        out_last[0] = (float)(100.0 * 0.99 + (double)clampv * 0.01);
    }
}

extern "C" void kernel_launch(void* const* d_in, const int* in_sizes, int n_in,
                              void* d_out, int out_size, void* d_ws, size_t ws_size,
                              hipStream_t stream) {
    const float* x = (const float*)d_in[0];
    long n = (long)in_sizes[0];
    float* out = (float*)d_out;
    unsigned int* ws = (unsigned int*)d_ws;

    // k = round(0.9999 * n) - 1, same double arithmetic as Python
    long k = (long)llround((99.99 / 100.0) * (double)n) - 1;
    if (k < 0) k = 0;
    if (k >= n) k = n - 1;

    long avail = (long)(ws_size / 4) - WS_CAND;
    if (avail < 0) avail = 0;
    if (avail > (1L << 22)) avail = (1L << 22);
    unsigned int cap = (unsigned int)avail;

    size_t hdr = (size_t)(WS_HIST + HIST_WORDS) * sizeof(unsigned int);
    if (hdr > ws_size) hdr = ws_size;
    hipMemsetAsync(d_ws, 0, hdr, stream);

    const int blocks = 4096;
    k_max_hist<<<blocks, 256, 0, stream>>>(x, n, ws);
    k_scan<<<1, 256, 0, stream>>>(ws, k);
    k_quant<<<blocks, 256, 0, stream>>>(x, out, n, ws, cap);
    k_select<<<1, 256, 0, stream>>>(ws, out + n, cap);
}

// Round 3
// 588.544 us; speedup vs baseline: 1.1241x; 1.1241x over previous
//
#include <hip/hip_runtime.h>
#include <math.h>

// Workspace layout (uint32 words):
//  [0] maxbits   (written by k_scan after reducing per-block maxes)
//  [1] sel_bin   (top-12-bit bin containing rank k)
//  [2] rank_in_bin
//  [4 .. 4+4096)          global histogram over top 12 bits of |x| bits
//  [4100 .. 4100+1024)    per-block max bits
//  [5124 .. 5124+1024)    per-block candidate counts
//  [6160 .. 6160+1024*256) per-block candidate segments (CAP=256 each)
#define WS_MAXBITS 0
#define WS_SELBIN  1
#define WS_RANK    2
#define WS_HIST    4
#define HIST_WORDS 4096
#define WS_BMAX    4100
#define WS_CNT     5124
#define WS_CAND    6160
#define NBLK       1024
#define CAP        256

// clang-native vector type: __builtin_nontemporal_store requires it
// (HIP's float4 is a class and is rejected).
typedef float floatx4 __attribute__((ext_vector_type(4)));

extern "C" __global__ void __launch_bounds__(256)
k_max_hist(const float* __restrict__ x, long n, unsigned int* __restrict__ ws) {
    __shared__ unsigned int lhist[HIST_WORDS];
    __shared__ unsigned int wred[4];
    for (int i = threadIdx.x; i < HIST_WORDS; i += 256) lhist[i] = 0;
    __syncthreads();

    long n4 = n >> 2;
    const float4* x4 = (const float4*)x;
    unsigned int mymax = 0;
    long stride = (long)gridDim.x * 256;
    long i = (long)blockIdx.x * 256 + threadIdx.x;
    // unroll-2: two independent loads in flight
    for (; i + stride < n4; i += 2 * stride) {
        float4 v0 = x4[i];
        float4 v1 = x4[i + stride];
        unsigned int a0 = __float_as_uint(fabsf(v0.x));
        unsigned int a1 = __float_as_uint(fabsf(v0.y));
        unsigned int a2 = __float_as_uint(fabsf(v0.z));
        unsigned int a3 = __float_as_uint(fabsf(v0.w));
        unsigned int b0 = __float_as_uint(fabsf(v1.x));
        unsigned int b1 = __float_as_uint(fabsf(v1.y));
        unsigned int b2 = __float_as_uint(fabsf(v1.z));
        unsigned int b3 = __float_as_uint(fabsf(v1.w));
        mymax = max(mymax, max(max(a0, a1), max(a2, a3)));
        mymax = max(mymax, max(max(b0, b1), max(b2, b3)));
        atomicAdd(&lhist[a0 >> 20], 1u);
        atomicAdd(&lhist[a1 >> 20], 1u);
        atomicAdd(&lhist[a2 >> 20], 1u);
        atomicAdd(&lhist[a3 >> 20], 1u);
        atomicAdd(&lhist[b0 >> 20], 1u);
        atomicAdd(&lhist[b1 >> 20], 1u);
        atomicAdd(&lhist[b2 >> 20], 1u);
        atomicAdd(&lhist[b3 >> 20], 1u);
    }
    for (; i < n4; i += stride) {
        float4 v = x4[i];
        unsigned int a0 = __float_as_uint(fabsf(v.x));
        unsigned int a1 = __float_as_uint(fabsf(v.y));
        unsigned int a2 = __float_as_uint(fabsf(v.z));
        unsigned int a3 = __float_as_uint(fabsf(v.w));
        mymax = max(mymax, max(max(a0, a1), max(a2, a3)));
        atomicAdd(&lhist[a0 >> 20], 1u);
        atomicAdd(&lhist[a1 >> 20], 1u);
        atomicAdd(&lhist[a2 >> 20], 1u);
        atomicAdd(&lhist[a3 >> 20], 1u);
    }
    // scalar tail (n % 4): fold into block 0's local state (no global atomics)
    if (blockIdx.x == 0 && threadIdx.x < (int)(n & 3)) {
        unsigned int a = __float_as_uint(fabsf(x[n4 * 4 + threadIdx.x]));
        mymax = max(mymax, a);
        atomicAdd(&lhist[a >> 20], 1u);
    }

    // wave64 max reduce → block reduce → plain store (no contended atomicMax)
    for (int off = 32; off > 0; off >>= 1)
        mymax = max(mymax, __shfl_down(mymax, off, 64));
    int lane = threadIdx.x & 63, wid = threadIdx.x >> 6;
    if (lane == 0) wred[wid] = mymax;
    __syncthreads();   // also orders all lhist atomics before the flush below
    if (threadIdx.x == 0) {
        ws[WS_BMAX + blockIdx.x] =
            max(max(wred[0], wred[1]), max(wred[2], wred[3]));
    }
    // flush LDS histogram with per-block rotated start so concurrent blocks
    // hit distinct global addresses (only ~300 bins are nonzero for N(0,1))
    unsigned int rot = (blockIdx.x * 1297u) & (HIST_WORDS - 1);
    for (int idx = threadIdx.x; idx < HIST_WORDS; idx += 256) {
        unsigned int bin = (idx + rot) & (HIST_WORDS - 1);
        unsigned int c = lhist[bin];
        if (c) atomicAdd(&ws[WS_HIST + bin], c);
    }
}

extern "C" __global__ void __launch_bounds__(256)
k_scan(unsigned int* __restrict__ ws, long k) {
    // single block: reduce per-block maxes; find bin containing rank k
    __shared__ unsigned long long partial[256];
    __shared__ unsigned int mred[256];
    const unsigned int* hist = ws + WS_HIST;

    unsigned int m = 0;
    for (int s = threadIdx.x; s < NBLK; s += 256) m = max(m, ws[WS_BMAX + s]);
    mred[threadIdx.x] = m;

    int base = threadIdx.x * (HIST_WORDS / 256);  // 16 bins per thread
    unsigned long long s = 0;
    for (int i = 0; i < 16; i++) s += hist[base + i];
    partial[threadIdx.x] = s;
    __syncthreads();
    if (threadIdx.x == 0) {
        unsigned int mm = 0;
        for (int t = 0; t < 256; t++) mm = max(mm, mred[t]);
        ws[WS_MAXBITS] = mm;

        unsigned long long acc = 0;
        long bin = -1;
        unsigned long long before = 0;
        for (int t = 0; t < 256; t++) {
            unsigned long long ps = partial[t];
            if (bin < 0 && acc + ps > (unsigned long long)k) {
                unsigned long long a2 = acc;
                for (int i = 0; i < 16; i++) {
                    unsigned int c = hist[t * 16 + i];
                    if (a2 + c > (unsigned long long)k) { bin = t * 16 + i; before = a2; break; }
                    a2 += c;
                }
            }
            acc += ps;
        }
        ws[WS_SELBIN] = (unsigned int)bin;
        ws[WS_RANK]   = (unsigned int)((unsigned long long)k - before);
    }
}

extern "C" __global__ void __launch_bounds__(256)
k_quant(const float* __restrict__ x, float* __restrict__ out, long n,
        unsigned int* __restrict__ ws) {
    __shared__ unsigned int lbuf[CAP];
    __shared__ unsigned int lcnt;
    if (threadIdx.x == 0) lcnt = 0;
    __syncthreads();

    float xmax = __uint_as_float(ws[WS_MAXBITS]);
    unsigned int selbin = ws[WS_SELBIN];
    float scale = 127.0f / xmax;
    float inv = 1.0f / scale;

    long n4 = n >> 2;
    const float4* x4 = (const float4*)x;
    floatx4* out4 = (floatx4*)out;
    long stride = (long)gridDim.x * 256;
    long i = (long)blockIdx.x * 256 + threadIdx.x;
    for (; i + stride < n4; i += 2 * stride) {
        float4 v0 = x4[i];
        float4 v1 = x4[i + stride];
        floatx4 r0, r1;
        r0.x = fminf(fmaxf(rintf(v0.x * scale), -127.0f), 127.0f) * inv;
        r0.y = fminf(fmaxf(rintf(v0.y * scale), -127.0f), 127.0f) * inv;
        r0.z = fminf(fmaxf(rintf(v0.z * scale), -127.0f), 127.0f) * inv;
        r0.w = fminf(fmaxf(rintf(v0.w * scale), -127.0f), 127.0f) * inv;
        r1.x = fminf(fmaxf(rintf(v1.x * scale), -127.0f), 127.0f) * inv;
        r1.y = fminf(fmaxf(rintf(v1.y * scale), -127.0f), 127.0f) * inv;
        r1.z = fminf(fmaxf(rintf(v1.z * scale), -127.0f), 127.0f) * inv;
        r1.w = fminf(fmaxf(rintf(v1.w * scale), -127.0f), 127.0f) * inv;
        __builtin_nontemporal_store(r0, &out4[i]);
        __builtin_nontemporal_store(r1, &out4[i + stride]);
        unsigned int a0 = __float_as_uint(fabsf(v0.x));
        unsigned int a1 = __float_as_uint(fabsf(v0.y));
        unsigned int a2 = __float_as_uint(fabsf(v0.z));
        unsigned int a3 = __float_as_uint(fabsf(v0.w));
        unsigned int b0 = __float_as_uint(fabsf(v1.x));
        unsigned int b1 = __float_as_uint(fabsf(v1.y));
        unsigned int b2 = __float_as_uint(fabsf(v1.z));
        unsigned int b3 = __float_as_uint(fabsf(v1.w));
        if ((a0 >> 20) == selbin) { unsigned int p = atomicAdd(&lcnt, 1u); if (p < CAP) lbuf[p] = a0; }
        if ((a1 >> 20) == selbin) { unsigned int p = atomicAdd(&lcnt, 1u); if (p < CAP) lbuf[p] = a1; }
        if ((a2 >> 20) == selbin) { unsigned int p = atomicAdd(&lcnt, 1u); if (p < CAP) lbuf[p] = a2; }
        if ((a3 >> 20) == selbin) { unsigned int p = atomicAdd(&lcnt, 1u); if (p < CAP) lbuf[p] = a3; }
        if ((b0 >> 20) == selbin) { unsigned int p = atomicAdd(&lcnt, 1u); if (p < CAP) lbuf[p] = b0; }
        if ((b1 >> 20) == selbin) { unsigned int p = atomicAdd(&lcnt, 1u); if (p < CAP) lbuf[p] = b1; }
        if ((b2 >> 20) == selbin) { unsigned int p = atomicAdd(&lcnt, 1u); if (p < CAP) lbuf[p] = b2; }
        if ((b3 >> 20) == selbin) { unsigned int p = atomicAdd(&lcnt, 1u); if (p < CAP) lbuf[p] = b3; }
    }
    for (; i < n4; i += stride) {
        float4 v = x4[i];
        floatx4 r;
        r.x = fminf(fmaxf(rintf(v.x * scale), -127.0f), 127.0f) * inv;
        r.y = fminf(fmaxf(rintf(v.y * scale), -127.0f), 127.0f) * inv;
        r.z = fminf(fmaxf(rintf(v.z * scale), -127.0f), 127.0f) * inv;
        r.w = fminf(fmaxf(rintf(v.w * scale), -127.0f), 127.0f) * inv;
        __builtin_nontemporal_store(r, &out4[i]);
        unsigned int a0 = __float_as_uint(fabsf(v.x));
        unsigned int a1 = __float_as_uint(fabsf(v.y));
        unsigned int a2 = __float_as_uint(fabsf(v.z));
        unsigned int a3 = __float_as_uint(fabsf(v.w));
        if ((a0 >> 20) == selbin) { unsigned int p = atomicAdd(&lcnt, 1u); if (p < CAP) lbuf[p] = a0; }
        if ((a1 >> 20) == selbin) { unsigned int p = atomicAdd(&lcnt, 1u); if (p < CAP) lbuf[p] = a1; }
        if ((a2 >> 20) == selbin) { unsigned int p = atomicAdd(&lcnt, 1u); if (p < CAP) lbuf[p] = a2; }
        if ((a3 >> 20) == selbin) { unsigned int p = atomicAdd(&lcnt, 1u); if (p < CAP) lbuf[p] = a3; }
    }
    // scalar tail
    if (blockIdx.x == 0 && threadIdx.x < (int)(n & 3)) {
        long t = n4 * 4 + threadIdx.x;
        float v = x[t];
        out[t] = fminf(fmaxf(rintf(v * scale), -127.0f), 127.0f) * inv;
        unsigned int a = __float_as_uint(fabsf(v));
        if ((a >> 20) == selbin) { unsigned int p = atomicAdd(&lcnt, 1u); if (p < CAP) lbuf[p] = a; }
    }
    __syncthreads();
    unsigned int c = lcnt; if (c > CAP) c = CAP;
    unsigned int* seg = ws + WS_CAND + (unsigned int)blockIdx.x * CAP;
    for (unsigned int e = threadIdx.x; e < c; e += 256) seg[e] = lbuf[e];
    if (threadIdx.x == 0) ws[WS_CNT + blockIdx.x] = c;
}

extern "C" __global__ void __launch_bounds__(256)
k_select(unsigned int* __restrict__ ws, float* __restrict__ out_last) {
    // single block: two-level radix select over per-block candidate segments.
    // All candidates share the same top-12 bits (sel_bin); resolve bits
    // [10,20) then [0,10) exactly.
    __shared__ unsigned int hist[1024];
    __shared__ unsigned int s_b1, s_j2;
    unsigned int j = ws[WS_RANK];
    unsigned int selbin = ws[WS_SELBIN];

    for (int i = threadIdx.x; i < 1024; i += 256) hist[i] = 0;
    __syncthreads();
    for (int s = threadIdx.x; s < NBLK; s += 256) {
        unsigned int c = ws[WS_CNT + s]; if (c > CAP) c = CAP;
        const unsigned int* seg = ws + WS_CAND + (unsigned int)s * CAP;
        for (unsigned int e = 0; e < c; e++)
            atomicAdd(&hist[(seg[e] >> 10) & 1023], 1u);
    }
    __syncthreads();
    if (threadIdx.x == 0) {
        unsigned int acc = 0, b1 = 1023;
        for (int b = 0; b < 1024; b++) {
            unsigned int h = hist[b];
            if (acc + h > j) { b1 = (unsigned int)b; break; }
            acc += h;
        }
        s_b1 = b1; s_j2 = j - acc;
    }
    __syncthreads();
    unsigned int pref = (selbin << 10) | s_b1;
    unsigned int j2 = s_j2;
    for (int i = threadIdx.x; i < 1024; i += 256) hist[i] = 0;
    __syncthreads();
    for (int s = threadIdx.x; s < NBLK; s += 256) {
        unsigned int c = ws[WS_CNT + s]; if (c > CAP) c = CAP;
        const unsigned int* seg = ws + WS_CAND + (unsigned int)s * CAP;
        for (unsigned int e = 0; e < c; e++) {
            unsigned int u = seg[e];
            if ((u >> 10) == pref) atomicAdd(&hist[u & 1023], 1u);
        }
    }
    __syncthreads();
    if (threadIdx.x == 0) {
        unsigned int acc = 0, b2 = 1023;
        for (int b = 0; b < 1024; b++) {
            unsigned int h = hist[b];
            if (acc + h > j2) { b2 = (unsigned int)b; break; }
            acc += h;
        }
        float clampv = __uint_as_float((pref << 10) | b2);
        // new_buffer = CLAMP_INIT*GAMMA + clamp_value*(1-GAMMA)
        out_last[0] = (float)(100.0 * 0.99 + (double)clampv * 0.01);
    }
}

extern "C" void kernel_launch(void* const* d_in, const int* in_sizes, int n_in,
                              void* d_out, int out_size, void* d_ws, size_t ws_size,
                              hipStream_t stream) {
    const float* x = (const float*)d_in[0];
    long n = (long)in_sizes[0];
    float* out = (float*)d_out;
    unsigned int* ws = (unsigned int*)d_ws;

    // k = round(0.9999 * n) - 1, same double arithmetic as Python
    long k = (long)llround((99.99 / 100.0) * (double)n) - 1;
    if (k < 0) k = 0;
    if (k >= n) k = n - 1;

    // zero only the global histogram (everything else is fully overwritten)
    (void)hipMemsetAsync((char*)d_ws + WS_HIST * sizeof(unsigned int), 0,
                         HIST_WORDS * sizeof(unsigned int), stream);

    k_max_hist<<<NBLK, 256, 0, stream>>>(x, n, ws);
    k_scan<<<1, 256, 0, stream>>>(ws, k);
    k_quant<<<NBLK, 256, 0, stream>>>(x, out, n, ws);
    k_select<<<1, 256, 0, stream>>>(ws, out + n);
}